// Round 1
// baseline (105.037 us; speedup 1.0000x reference)
//
#include <hip/hip_runtime.h>
#include <math.h>

constexpr int E_EDGES = 4194304;
constexpr float EPS_W = 1e-8f;

__global__ __launch_bounds__(256) void ba_kernel(
    const float*  __restrict__ poses,      // 2048*7
    const float2* __restrict__ pc_rt,      // 524288 x (r,theta)
    const float*  __restrict__ elev,       // 524288
    const float*  __restrict__ scale,      // 2
    const float2* __restrict__ baseline,   // E
    const float2* __restrict__ weights2,   // E pairs (2E floats)
    const int*    __restrict__ patch_idx,  // E
    const int*    __restrict__ inv_idx,    // E
    const int*    __restrict__ src_idx,    // E
    const int*    __restrict__ tgt_idx,    // E
    float2*       __restrict__ out)        // E pairs
{
    const float sx = scale[0];
    const float sy = scale[1];
    const int stride = gridDim.x * blockDim.x;
    for (int e = blockIdx.x * blockDim.x + threadIdx.x; e < E_EDGES; e += stride) {
        const int pi = patch_idx[e];
        const int ii = inv_idx[e];
        const int si = src_idx[e];
        const int ti = tgt_idx[e];

        const float2 pc  = pc_rt[pi];
        const float  phi = elev[ii];

        float sphi, cphi, sth, cth;
        __sincosf(phi,  &sphi, &cphi);
        __sincosf(pc.y, &sth,  &cth);

        const float rcp = pc.x * cphi;
        const float lx = rcp * cth;
        const float ly = rcp * sth;
        const float lz = pc.x * sphi;

        // source pose: rotate local_src by q, then translate
        const float* P = poses + (size_t)si * 7;
        const float spx = P[0], spy = P[1], spz = P[2];
        const float qx = P[3], qy = P[4], qz = P[5], qw = P[6];

        const float t0 = 2.0f * (qy * lz - qz * ly);
        const float t1 = 2.0f * (qz * lx - qx * lz);
        const float t2 = 2.0f * (qx * ly - qy * lx);
        const float gx = lx + qw * t0 + (qy * t2 - qz * t1) + spx;
        const float gy = ly + qw * t1 + (qz * t0 - qx * t2) + spy;
        const float gz = lz + qw * t2 + (qx * t1 - qy * t0) + spz;

        // target pose: translate back, rotate by conj(q)
        const float* T = poses + (size_t)ti * 7;
        const float dx = gx - T[0];
        const float dy = gy - T[1];
        const float dz = gz - T[2];
        const float uqx = -T[3], uqy = -T[4], uqz = -T[5], uqw = T[6];

        const float u0 = 2.0f * (uqy * dz - uqz * dy);
        const float u1 = 2.0f * (uqz * dx - uqx * dz);
        const float u2 = 2.0f * (uqx * dy - uqy * dx);
        const float ox = dx + uqw * u0 + (uqy * u2 - uqz * u1);
        const float oy = dy + uqw * u1 + (uqz * u0 - uqx * u2);
        const float oz = dz + uqw * u2 + (uqx * u1 - uqy * u0);

        const float r2  = sqrtf(ox * ox + oy * oy + oz * oz);
        const float th2 = atan2f(oy, ox);

        const float2 bl = baseline[e];
        const float2 w  = weights2[e];
        float2 o;
        o.x = (r2  * sx - bl.x) * sqrtf(w.x + EPS_W);
        o.y = (th2 * sy - bl.y) * sqrtf(w.y + EPS_W);
        out[e] = o;
    }
}

extern "C" void kernel_launch(void* const* d_in, const int* in_sizes, int n_in,
                              void* d_out, int out_size, void* d_ws, size_t ws_size,
                              hipStream_t stream) {
    const float*  poses    = (const float*)d_in[0];
    const float2* pc_rt    = (const float2*)d_in[1];
    const float*  elev     = (const float*)d_in[2];
    const float*  scale    = (const float*)d_in[3];
    const float2* baseline = (const float2*)d_in[4];
    const float2* weights2 = (const float2*)d_in[5];
    const int*    patch_i  = (const int*)d_in[6];
    const int*    inv_i    = (const int*)d_in[7];
    const int*    src_i    = (const int*)d_in[8];
    const int*    tgt_i    = (const int*)d_in[9];
    float2*       out      = (float2*)d_out;

    dim3 grid(2048), block(256);
    hipLaunchKernelGGL(ba_kernel, grid, block, 0, stream,
                       poses, pc_rt, elev, scale, baseline, weights2,
                       patch_i, inv_i, src_i, tgt_i, out);
}